// Round 4
// baseline (286.699 us; speedup 1.0000x reference)
//
#include <hip/hip_runtime.h>

#define Bn 8
#define Cn 512
#define Hn 8
#define Dn 64
#define Nn 1024
#define SCALEQ 0.125f

typedef unsigned short u16;
typedef unsigned short u16x8 __attribute__((ext_vector_type(8)));
typedef unsigned short u16x4 __attribute__((ext_vector_type(4)));
typedef short s16x4 __attribute__((ext_vector_type(4)));
typedef float f32x4 __attribute__((ext_vector_type(4)));
typedef __bf16 bf16x8 __attribute__((ext_vector_type(8)));

__device__ __forceinline__ u16 f2bf(float f){
  unsigned u = __float_as_uint(f);
  u += 0x7fffu + ((u >> 16) & 1u);   // RNE
  return (u16)(u >> 16);
}
__device__ __forceinline__ float bf2f(u16 h){
  return __uint_as_float(((unsigned)h) << 16);
}
__device__ __forceinline__ f32x4 mfma16(u16x8 a, u16x8 b, f32x4 c){
  return __builtin_amdgcn_mfma_f32_16x16x32_bf16(
      __builtin_bit_cast(bf16x8, a), __builtin_bit_cast(bf16x8, b), c, 0, 0, 0);
}
// K=16 variant: A/B layout (lane r,g holds k=4g+j) == 16x16 C/D layout (row=4g+rr) -> P stays in regs
__device__ __forceinline__ f32x4 mfma16k16(u16x4 a, u16x4 b, f32x4 c){
  return __builtin_amdgcn_mfma_f32_16x16x16bf16_1k(
      __builtin_bit_cast(s16x4, a), __builtin_bit_cast(s16x4, b), c, 0, 0, 0);
}

// ---------------- pre-pass: f32 -> bf16 weight convert ----------------
__global__ __launch_bounds__(256) void k_convert(const float* __restrict__ src,
                                                 u16* __restrict__ dst, int n4){
  int i = blockIdx.x * 256 + threadIdx.x;
  if (i >= n4) return;
  float4 f = reinterpret_cast<const float4*>(src)[i];
  u16x4 o;
  o[0] = f2bf(f.x); o[1] = f2bf(f.y); o[2] = f2bf(f.z); o[3] = f2bf(f.w);
  reinterpret_cast<u16x4*>(dst)[i] = o;
}

// ---------------- pre-pass: fmap [B][C][N] f32 -> fmapT [B][N][C] bf16 ----------------
__global__ __launch_bounds__(256) void k_transpose(const float* __restrict__ fmap,
                                                   u16* __restrict__ fmapT){
  __shared__ float tile[32][33];
  const int n0 = blockIdx.x * 32, c0 = blockIdx.y * 32, b = blockIdx.z;
  const int tx = threadIdx.x & 31, ty = threadIdx.x >> 5;   // 32 x 8
  const float* src = fmap + ((size_t)b * Cn + c0) * Nn + n0;
#pragma unroll
  for (int i = 0; i < 4; i++) tile[ty + 8*i][tx] = src[(size_t)(ty + 8*i) * Nn + tx];
  __syncthreads();
  u16* dst = fmapT + ((size_t)b * Nn + n0) * Cn + c0;
#pragma unroll
  for (int i = 0; i < 4; i++) dst[(size_t)(ty + 8*i) * Cn + tx] = f2bf(tile[tx][ty + 8*i]);
}

// ---------------- NT GEMM core with register double-buffer prefetch ----------------
__device__ __forceinline__ void gemm_ld(const u16* pa, const u16* pb, int lda, int ldb, int kc,
                                        u16x8 (&af)[4], u16x8 (&bf)[4]){
#pragma unroll
  for (int t = 0; t < 4; t++) af[t] = *reinterpret_cast<const u16x8*>(pa + (size_t)t*16*lda + kc);
#pragma unroll
  for (int t = 0; t < 4; t++) bf[t] = *reinterpret_cast<const u16x8*>(pb + (size_t)t*16*ldb + kc);
}
__device__ __forceinline__ void gemm_fma(const u16x8 (&af)[4], const u16x8 (&bf)[4],
                                         f32x4 (&acc)[4][4]){
#pragma unroll
  for (int i = 0; i < 4; i++)
#pragma unroll
    for (int j = 0; j < 4; j++)
      acc[i][j] = mfma16(af[i], bf[j], acc[i][j]);
}
// D[i][j] = sum_k A[i*lda+k]*B[j*ldb+k], K = Cn = 512, 64x64 per wave
__device__ __forceinline__ void gemm_nt_64x64(const u16* __restrict__ Ap, int lda,
                                              const u16* __restrict__ Bp, int ldb,
                                              f32x4 (&acc)[4][4]){
  const int lane = threadIdx.x & 63;
  const int r = lane & 15, g = lane >> 4;
  const u16* pa = Ap + (size_t)r * lda + 8 * g;
  const u16* pb = Bp + (size_t)r * ldb + 8 * g;
  u16x8 aA[4], bA[4], aB[4], bB[4];
  gemm_ld(pa, pb, lda, ldb, 0, aA, bA);
  for (int kc = 0; kc < Cn; kc += 64){
    gemm_ld(pa, pb, lda, ldb, kc + 32, aB, bB);           // prefetch while computing A
    gemm_fma(aA, bA, acc);
    gemm_ld(pa, pb, lda, ldb, (kc + 64) & (Cn - 1), aA, bA);  // wraps harmlessly on last iter
    gemm_fma(aB, bB, acc);
  }
}

// ---------------- GEMM1: qkvL = Wqkvl @ fmap  (per batch) ----------------
__global__ __launch_bounds__(256) void k_gemm1(const u16* __restrict__ fmapT, // [B][N][C]
                                               const u16* __restrict__ W1,    // [2048][C]
                                               u16* __restrict__ Qb, u16* __restrict__ Kb,
                                               u16* __restrict__ Vt, u16* __restrict__ Lb){
  const int ob = blockIdx.x;           // 16 o-blocks of 128
  const int nb = blockIdx.y;           // 8 n-blocks of 128
  const int b  = blockIdx.z;
  const int w = threadIdx.x >> 6, wi = w >> 1, wj = w & 1;
  const int lane = threadIdx.x & 63, r = lane & 15, g = lane >> 4;
  const int seg = ob >> 2;             // 0=Q 1=K 2=V 3=L

  f32x4 acc[4][4];
  const f32x4 z = {0.f, 0.f, 0.f, 0.f};
#pragma unroll
  for (int i = 0; i < 4; i++)
#pragma unroll
    for (int j = 0; j < 4; j++) acc[i][j] = z;

  const u16* fbase = fmapT + (size_t)b * Nn * Cn;

  if (seg != 2){
    const u16* Ap = fbase + (size_t)(nb*128 + wi*64) * Cn;
    const u16* Bp = W1 + (size_t)(ob*128 + wj*64) * Cn;
    gemm_nt_64x64(Ap, Cn, Bp, Cn, acc);
    u16* dst = (seg == 0) ? Qb : (seg == 1 ? Kb : Lb);
    const float sc = (seg == 0) ? SCALEQ : 1.0f;
#pragma unroll
    for (int it = 0; it < 4; it++)
#pragma unroll
      for (int jt = 0; jt < 4; jt++)
#pragma unroll
        for (int rr = 0; rr < 4; rr++){
          int n = nb*128 + wi*64 + it*16 + 4*g + rr;
          int o = ob*128 + wj*64 + jt*16 + r;
          dst[((size_t)b * Nn + n) * Cn + (o & 511)] = f2bf(acc[it][jt][rr] * sc);
        }
  } else {
    const u16* Ap = W1 + (size_t)(ob*128 + wi*64) * Cn;
    const u16* Bp = fbase + (size_t)(nb*128 + wj*64) * Cn;
    gemm_nt_64x64(Ap, Cn, Bp, Cn, acc);
#pragma unroll
    for (int it = 0; it < 4; it++)
#pragma unroll
      for (int jt = 0; jt < 4; jt++)
#pragma unroll
        for (int rr = 0; rr < 4; rr++){
          int o = ob*128 + wi*64 + it*16 + 4*g + rr;
          int oo = o - 1024;
          int h = oo >> 6, d = oo & 63;
          int n = nb*128 + wj*64 + jt*16 + r;
          Vt[(((size_t)b * Hn + h) * Dn + d) * Nn + n] = f2bf(acc[it][jt][rr]);
        }
  }
}

// ---------------- attention: swapped flash, reg-P, reg double-buffered K/V prefetch ----------
__device__ __forceinline__ void attn_ld(const u16* kbase, const u16* vbase, int kt, int r, int g,
                                        u16x8 (&kf)[8], u16x4 (&vf)[16]){
#pragma unroll
  for (int t = 0; t < 4; t++){
    const u16* kr = kbase + (size_t)(kt + 16*t + r) * Cn + 8*g;
    kf[2*t]   = *reinterpret_cast<const u16x8*>(kr);
    kf[2*t+1] = *reinterpret_cast<const u16x8*>(kr + 32);
  }
#pragma unroll
  for (int s = 0; s < 4; s++)
#pragma unroll
    for (int dt = 0; dt < 4; dt++)
      vf[s*4+dt] = *reinterpret_cast<const u16x4*>(
          vbase + (size_t)(dt*16 + r) * Nn + kt + 16*s + 4*g);
}

__device__ __forceinline__ void attn_body(const u16x8 (&kf)[8], const u16x4 (&vf)[16],
                                          u16x8 qf0, u16x8 qf1,
                                          float& m, float& lsum, f32x4 (&accO)[4]){
  const f32x4 z = {0.f, 0.f, 0.f, 0.f};
  f32x4 st[4];
#pragma unroll
  for (int t = 0; t < 4; t++){
    st[t] = mfma16(kf[2*t], qf0, z);
    st[t] = mfma16(kf[2*t+1], qf1, st[t]);
  }
  float tm = -1e30f;
#pragma unroll
  for (int t = 0; t < 4; t++)
    tm = fmaxf(tm, fmaxf(fmaxf(st[t][0], st[t][1]), fmaxf(st[t][2], st[t][3])));
  tm = fmaxf(tm, __shfl_xor(tm, 16));
  tm = fmaxf(tm, __shfl_xor(tm, 32));
  if (__any(tm - m > 8.f)){          // defer-max (T13)
    float mn = fmaxf(m, tm);
    float al = __expf(m - mn);
    m = mn;
    lsum *= al;
#pragma unroll
    for (int dt = 0; dt < 4; dt++) accO[dt] *= al;
  }
  u16x4 p[4];
  float ls = 0.f;
#pragma unroll
  for (int t = 0; t < 4; t++){
#pragma unroll
    for (int j = 0; j < 4; j++){
      float e = __expf(st[t][j] - m);
      ls += e;
      p[t][j] = f2bf(e);
    }
  }
  lsum += ls;
#pragma unroll
  for (int s = 0; s < 4; s++)
#pragma unroll
    for (int dt = 0; dt < 4; dt++)
      accO[dt] = mfma16k16(vf[s*4+dt], p[s], accO[dt]);
}

__global__ __launch_bounds__(256) void k_attn(const u16* __restrict__ Qb,  // [B][N][C] (pre-scaled)
                                              const u16* __restrict__ Kb,  // [B][N][C]
                                              const u16* __restrict__ Vt,  // [B][H][D][N]
                                              const u16* __restrict__ Lb,  // [B][N][C]
                                              u16* __restrict__ tok){      // [B][N][C]
  // XCD-bijective swizzle: the 16 q-blocks of one (b,h) share one XCD's L2
  const int bid = blockIdx.x;
  const int w0 = (bid & 7) * 128 + (bid >> 3);
  const int qblk = w0 & 15, h = (w0 >> 4) & 7, b = w0 >> 7;
  const int w = threadIdx.x >> 6, lane = threadIdx.x & 63;
  const int r = lane & 15, g = lane >> 4;
  const int q0 = qblk * 64 + w * 16;

  const u16* qrow = Qb + ((size_t)b * Nn + q0 + r) * Cn + h * Dn + 8 * g;
  u16x8 qf0 = *reinterpret_cast<const u16x8*>(qrow);
  u16x8 qf1 = *reinterpret_cast<const u16x8*>(qrow + 32);

  const u16* kbase = Kb + (size_t)b * Nn * Cn + h * Dn;
  const u16* vbase = Vt + ((size_t)b * Hn + h) * Dn * Nn;

  f32x4 accO[4];
  const f32x4 z = {0.f, 0.f, 0.f, 0.f};
#pragma unroll
  for (int dt = 0; dt < 4; dt++) accO[dt] = z;
  float m = -1e30f, lsum = 0.f;

  u16x8 kA[8], kB[8];
  u16x4 vA[16], vB[16];
  attn_ld(kbase, vbase, 0, r, g, kA, vA);
  for (int kt = 0; kt < Nn; kt += 128){
    attn_ld(kbase, vbase, kt + 64, r, g, kB, vB);            // prefetch next tile
    attn_body(kA, vA, qf0, qf1, m, lsum, accO);
    attn_ld(kbase, vbase, (kt + 128) & (Nn - 1), r, g, kA, vA);  // wraps harmlessly at end
    attn_body(kB, vB, qf0, qf1, m, lsum, accO);
  }

  // epilogue: cross-g lsum reduce, normalize, +L, write token-major bf16
  lsum += __shfl_xor(lsum, 16);
  lsum += __shfl_xor(lsum, 32);
  float linv = 1.0f / lsum;
  const int n = q0 + r;
  const u16* lrow = Lb + ((size_t)b * Nn + n) * Cn + h * Dn;
  u16* trow = tok + ((size_t)b * Nn + n) * Cn + h * Dn;
#pragma unroll
  for (int dt = 0; dt < 4; dt++){
    u16x4 lv = *reinterpret_cast<const u16x4*>(lrow + dt*16 + 4*g);
    u16x4 ov;
#pragma unroll
    for (int rr = 0; rr < 4; rr++)
      ov[rr] = f2bf(accO[dt][rr] * linv + bf2f(lv[rr]));
    *reinterpret_cast<u16x4*>(trow + dt*16 + 4*g) = ov;
  }
}

// ---------------- GEMM2: out = Wout @ tok + bout  -> f32 [B][C][N] ----------------
__global__ __launch_bounds__(256) void k_gemm2(const u16* __restrict__ tok, // [B][N][C]
                                               const u16* __restrict__ Wo,  // [C][C]
                                               const float* __restrict__ bout,
                                               float* __restrict__ out){
  const int ob = blockIdx.x;   // 4 o-blocks of 128
  const int nb = blockIdx.y;   // 8 n-blocks of 128
  const int b  = blockIdx.z;
  const int w = threadIdx.x >> 6, wi = w >> 1, wj = w & 1;
  const int lane = threadIdx.x & 63, r = lane & 15, g = lane >> 4;

  f32x4 acc[4][4];
  const f32x4 z = {0.f, 0.f, 0.f, 0.f};
#pragma unroll
  for (int i = 0; i < 4; i++)
#pragma unroll
    for (int j = 0; j < 4; j++) acc[i][j] = z;

  const u16* Ap = Wo + (size_t)(ob*128 + wi*64) * Cn;
  const u16* Bp = tok + (size_t)b * Nn * Cn + (size_t)(nb*128 + wj*64) * Cn;
  gemm_nt_64x64(Ap, Cn, Bp, Cn, acc);

#pragma unroll
  for (int it = 0; it < 4; it++)
#pragma unroll
    for (int jt = 0; jt < 4; jt++)
#pragma unroll
      for (int rr = 0; rr < 4; rr++){
        int o = ob*128 + wi*64 + it*16 + 4*g + rr;
        int n = nb*128 + wj*64 + jt*16 + r;
        out[((size_t)b * Cn + o) * Nn + n] = acc[it][jt][rr] + bout[o];
      }
}

extern "C" void kernel_launch(void* const* d_in, const int* in_sizes, int n_in,
                              void* d_out, int out_size, void* d_ws, size_t ws_size,
                              hipStream_t stream){
  const float* fmap  = (const float*)d_in[0];
  const float* Wqkvl = (const float*)d_in[1];
  const float* Wout  = (const float*)d_in[2];
  const float* bout  = (const float*)d_in[3];
  float* out = (float*)d_out;

  char* ws = (char*)d_ws;
  size_t off = 0;
  auto alloc = [&](size_t bytes) -> void* {
    void* p = ws + off;
    off += (bytes + 255) & ~(size_t)255;
    return p;
  };
  u16* W1bf  = (u16*)alloc((size_t)4*Cn*Cn*2);
  u16* Wobf  = (u16*)alloc((size_t)Cn*Cn*2);
  u16* fmapT = (u16*)alloc((size_t)Bn*Nn*Cn*2);
  u16* Qb    = (u16*)alloc((size_t)Bn*Nn*Cn*2);
  u16* Kb    = (u16*)alloc((size_t)Bn*Nn*Cn*2);
  u16* Lb    = (u16*)alloc((size_t)Bn*Nn*Cn*2);
  u16* Vt    = (u16*)alloc((size_t)Bn*Hn*Dn*Nn*2);
  u16* tok   = fmapT;   // fmapT dead after gemm1; reuse for attention output

  hipLaunchKernelGGL(k_convert, dim3((4*Cn*Cn/4 + 255)/256), dim3(256), 0, stream,
                     Wqkvl, W1bf, 4*Cn*Cn/4);
  hipLaunchKernelGGL(k_convert, dim3((Cn*Cn/4 + 255)/256), dim3(256), 0, stream,
                     Wout, Wobf, Cn*Cn/4);
  hipLaunchKernelGGL(k_transpose, dim3(Nn/32, Cn/32, Bn), dim3(256), 0, stream, fmap, fmapT);
  hipLaunchKernelGGL(k_gemm1, dim3(16, 8, Bn), dim3(256), 0, stream, fmapT, W1bf, Qb, Kb, Vt, Lb);
  hipLaunchKernelGGL(k_attn, dim3(1024), dim3(256), 0, stream, Qb, Kb, Vt, Lb, tok);
  hipLaunchKernelGGL(k_gemm2, dim3(4, 8, Bn), dim3(256), 0, stream, tok, Wobf, bout, out);
}

// Round 5
// 96.427 us; speedup vs baseline: 2.9732x; 2.9732x over previous
//
#include <hip/hip_runtime.h>

#define Bn 8
#define Cn 512
#define Hn 8
#define Dn 64
#define Nn 1024
#define SCALEQ 0.125f

typedef unsigned short u16;
typedef unsigned short u16x8 __attribute__((ext_vector_type(8)));
typedef unsigned short u16x4 __attribute__((ext_vector_type(4)));
typedef short s16x4 __attribute__((ext_vector_type(4)));
typedef float f32x4 __attribute__((ext_vector_type(4)));
typedef __bf16 bf16x8 __attribute__((ext_vector_type(8)));

__device__ __forceinline__ u16 f2bf(float f){
  unsigned u = __float_as_uint(f);
  u += 0x7fffu + ((u >> 16) & 1u);   // RNE
  return (u16)(u >> 16);
}
__device__ __forceinline__ float bf2f(u16 h){
  return __uint_as_float(((unsigned)h) << 16);
}
__device__ __forceinline__ f32x4 mfma16(u16x8 a, u16x8 b, f32x4 c){
  return __builtin_amdgcn_mfma_f32_16x16x32_bf16(
      __builtin_bit_cast(bf16x8, a), __builtin_bit_cast(bf16x8, b), c, 0, 0, 0);
}
// K=16: A/B layout (lane r,g holds k=4g+j) == 16x16 C/D layout -> P stays in registers
__device__ __forceinline__ f32x4 mfma16k16(u16x4 a, u16x4 b, f32x4 c){
  return __builtin_amdgcn_mfma_f32_16x16x16bf16_1k(
      __builtin_bit_cast(s16x4, a), __builtin_bit_cast(s16x4, b), c, 0, 0, 0);
}

// async global->LDS, 16B per lane; dst must be wave-uniform (HW adds lane*16B)
__device__ __forceinline__ void gload16(const u16* src, u16* dst){
  __builtin_amdgcn_global_load_lds(
      (const __attribute__((address_space(1))) unsigned int*)src,
      (__attribute__((address_space(3))) unsigned int*)dst, 16, 0, 0);
}

// ---------------- pre-pass: f32 -> bf16 weight convert ----------------
__global__ __launch_bounds__(256) void k_convert(const float* __restrict__ src,
                                                 u16* __restrict__ dst, int n4){
  int i = blockIdx.x * 256 + threadIdx.x;
  if (i >= n4) return;
  float4 f = reinterpret_cast<const float4*>(src)[i];
  u16x4 o;
  o[0] = f2bf(f.x); o[1] = f2bf(f.y); o[2] = f2bf(f.z); o[3] = f2bf(f.w);
  reinterpret_cast<u16x4*>(dst)[i] = o;
}

// ---------------- pre-pass: fmap [B][C][N] f32 -> fmapT [B][N][C] bf16 ----------------
__global__ __launch_bounds__(256) void k_transpose(const float* __restrict__ fmap,
                                                   u16* __restrict__ fmapT){
  __shared__ float tile[32][33];
  const int n0 = blockIdx.x * 32, c0 = blockIdx.y * 32, b = blockIdx.z;
  const int tx = threadIdx.x & 31, ty = threadIdx.x >> 5;   // 32 x 8
  const float* src = fmap + ((size_t)b * Cn + c0) * Nn + n0;
#pragma unroll
  for (int i = 0; i < 4; i++) tile[ty + 8*i][tx] = src[(size_t)(ty + 8*i) * Nn + tx];
  __syncthreads();
  u16* dst = fmapT + ((size_t)b * Nn + n0) * Cn + c0;
#pragma unroll
  for (int i = 0; i < 4; i++) dst[(size_t)(ty + 8*i) * Cn + tx] = f2bf(tile[tx][ty + 8*i]);
}

// ---- staging: 64 rows x 64 elem (128B rows, 8 chunks of 16B), swizzle chunk^=(row&7) ----
__device__ __forceinline__ void stage64(const u16* g, size_t ldg, u16* lbase, int w, int lane){
#pragma unroll
  for (int s = 0; s < 2; s++){
    int row = s*32 + w*8 + (lane>>3);
    const u16* src = g + (size_t)row*ldg + (((lane&7) ^ (row&7)) * 8);
    u16* dst = lbase + (s*32 + w*8)*64;   // wave-uniform; HW adds lane*16B
    gload16(src, dst);
  }
}
// ---- staging: 128 rows x 32 elem (64B rows, 4 chunks of 16B), swizzle chunk^=(row&3) ----
__device__ __forceinline__ void stage128x32(const u16* g, size_t ldg, u16* lbase, int w, int lane){
#pragma unroll
  for (int s = 0; s < 2; s++){
    int row = s*64 + w*16 + (lane>>2);
    const u16* src = g + (size_t)row*ldg + (((lane&3) ^ (row&3)) * 8);
    u16* dst = lbase + (s*64 + w*16)*32;
    gload16(src, dst);
  }
}

__device__ __forceinline__ void gemm_fma(const u16x8 (&af)[4], const u16x8 (&bf)[4],
                                         f32x4 (&acc)[4][4]){
#pragma unroll
  for (int i = 0; i < 4; i++)
#pragma unroll
    for (int j = 0; j < 4; j++)
      acc[i][j] = mfma16(af[i], bf[j], acc[i][j]);
}

// ---- NT GEMM 128x128 block tile, BK=32, LDS double-buffered, K = Cn ----
// D[i][j] = sum_k A[i*lda+k]*B[j*ldb+k]; wave (wi,wj) owns 64x64 quadrant
__device__ __forceinline__ void gemm_nt_128(const u16* __restrict__ Ap, int lda,
                                            const u16* __restrict__ Bp, int ldb,
                                            u16* sA, u16* sB,  // [2][128*32] each
                                            f32x4 (&acc)[4][4]){
  const int tid = threadIdx.x;
  const int w = tid >> 6, lane = tid & 63, r = lane & 15, g = lane >> 4;
  const int wi = w >> 1, wj = w & 1;
  stage128x32(Ap, lda, sA, w, lane);
  stage128x32(Bp, ldb, sB, w, lane);
  for (int ks = 0; ks < Cn/32; ks++){
    __syncthreads();                       // drains vmcnt -> buf[ks&1] ready; prior reads done
    const int cur = ks & 1;
    if (ks + 1 < Cn/32){
      stage128x32(Ap + (ks+1)*32, lda, sA + (cur^1)*128*32, w, lane);
      stage128x32(Bp + (ks+1)*32, ldb, sB + (cur^1)*128*32, w, lane);
    }
    const u16* Al = sA + cur*128*32;
    const u16* Bl = sB + cur*128*32;
    u16x8 af[4], bf[4];
#pragma unroll
    for (int t = 0; t < 4; t++){
      int ar = wi*64 + t*16 + r;
      af[t] = *reinterpret_cast<const u16x8*>(&Al[ar*32 + ((g ^ (ar&3)) * 8)]);
      int br = wj*64 + t*16 + r;
      bf[t] = *reinterpret_cast<const u16x8*>(&Bl[br*32 + ((g ^ (br&3)) * 8)]);
    }
    gemm_fma(af, bf, acc);
  }
}

// ---------------- GEMM1: qkvL = Wqkvl @ fmap  (per batch) ----------------
__global__ __launch_bounds__(256) void k_gemm1(const u16* __restrict__ fmapT, // [B][N][C]
                                               const u16* __restrict__ W1,    // [2048][C]
                                               u16* __restrict__ Qb, u16* __restrict__ Kb,
                                               u16* __restrict__ Vt, u16* __restrict__ Lb){
  __shared__ u16 sA[2*128*32], sB[2*128*32];
  const int ob = blockIdx.x;           // 16 o-blocks of 128
  const int nb = blockIdx.y;           // 8 n-blocks of 128
  const int b  = blockIdx.z;
  const int w = threadIdx.x >> 6, wi = w >> 1, wj = w & 1;
  const int lane = threadIdx.x & 63, r = lane & 15, g = lane >> 4;
  const int seg = ob >> 2;             // 0=Q 1=K 2=V 3=L

  f32x4 acc[4][4];
  const f32x4 z = {0.f, 0.f, 0.f, 0.f};
#pragma unroll
  for (int i = 0; i < 4; i++)
#pragma unroll
    for (int j = 0; j < 4; j++) acc[i][j] = z;

  const u16* fbase = fmapT + (size_t)b * Nn * Cn;

  if (seg != 2){
    gemm_nt_128(fbase + (size_t)(nb*128) * Cn, Cn, W1 + (size_t)(ob*128) * Cn, Cn, sA, sB, acc);
    u16* dst = (seg == 0) ? Qb : (seg == 1 ? Kb : Lb);
    const float sc = (seg == 0) ? SCALEQ : 1.0f;
#pragma unroll
    for (int it = 0; it < 4; it++)
#pragma unroll
      for (int jt = 0; jt < 4; jt++)
#pragma unroll
        for (int rr = 0; rr < 4; rr++){
          int n = nb*128 + wi*64 + it*16 + 4*g + rr;
          int o = ob*128 + wj*64 + jt*16 + r;
          dst[((size_t)b * Nn + n) * Cn + (o & 511)] = f2bf(acc[it][jt][rr] * sc);
        }
  } else {
    gemm_nt_128(W1 + (size_t)(ob*128) * Cn, Cn, fbase + (size_t)(nb*128) * Cn, Cn, sA, sB, acc);
#pragma unroll
    for (int it = 0; it < 4; it++)
#pragma unroll
      for (int jt = 0; jt < 4; jt++)
#pragma unroll
        for (int rr = 0; rr < 4; rr++){
          int o = ob*128 + wi*64 + it*16 + 4*g + rr;
          int oo = o - 1024;
          int h = oo >> 6, d = oo & 63;
          int n = nb*128 + wj*64 + jt*16 + r;
          Vt[(((size_t)b * Hn + h) * Dn + d) * Nn + n] = f2bf(acc[it][jt][rr]);
        }
  }
}

// ---------------- attention: swapped flash, LDS-staged K/V, reg-P ----------------
__global__ __launch_bounds__(256) void k_attn(const u16* __restrict__ Qb,  // [B][N][C] (pre-scaled)
                                              const u16* __restrict__ Kb,  // [B][N][C]
                                              const u16* __restrict__ Vt,  // [B][H][D][N]
                                              const u16* __restrict__ Lb,  // [B][N][C]
                                              u16* __restrict__ tok){      // [B][N][C]
  __shared__ u16 Kl[2*64*64], Vl[2*64*64];
  // XCD-bijective swizzle: the 16 q-blocks of one (b,h) share one XCD's L2
  const int bid = blockIdx.x;
  const int w0 = (bid & 7) * 128 + (bid >> 3);
  const int qblk = w0 & 15, h = (w0 >> 4) & 7, b = w0 >> 7;
  const int w = threadIdx.x >> 6, lane = threadIdx.x & 63;
  const int r = lane & 15, g = lane >> 4;
  const int q0 = qblk * 64 + w * 16;

  const u16* qrow = Qb + ((size_t)b * Nn + q0 + r) * Cn + h * Dn + 8 * g;
  u16x8 qf0 = *reinterpret_cast<const u16x8*>(qrow);
  u16x8 qf1 = *reinterpret_cast<const u16x8*>(qrow + 32);

  const u16* kbase = Kb + (size_t)b * Nn * Cn + h * Dn;   // rows: keys, 64-elem slice per row
  const u16* vbase = Vt + ((size_t)b * Hn + h) * Dn * Nn; // rows: d,   64-elem slice per tile

  f32x4 accO[4];
  const f32x4 z = {0.f, 0.f, 0.f, 0.f};
#pragma unroll
  for (int dt = 0; dt < 4; dt++) accO[dt] = z;
  float m = -1e30f, lsum = 0.f;

  stage64(kbase, Cn, Kl, w, lane);
  stage64(vbase, Nn, Vl, w, lane);

  for (int tile = 0; tile < 16; tile++){
    __syncthreads();                       // buf[tile&1] staged; prior reads done
    const int cur = tile & 1;
    if (tile + 1 < 16){
      stage64(kbase + (size_t)(tile+1)*64*Cn, Cn, Kl + (cur^1)*64*64, w, lane);
      stage64(vbase + (tile+1)*64,            Nn, Vl + (cur^1)*64*64, w, lane);
    }
    const u16* Kc = Kl + cur*64*64;
    const u16* Vc = Vl + cur*64*64;

    // QK^T (swapped): st[t][rr] = S[key = 16t+4g+rr][query r]
    f32x4 st[4];
#pragma unroll
    for (int t = 0; t < 4; t++){
      int row = 16*t + r;
      u16x8 k0 = *reinterpret_cast<const u16x8*>(&Kc[row*64 + ((g       ^ (r&7)) * 8)]);
      u16x8 k1 = *reinterpret_cast<const u16x8*>(&Kc[row*64 + (((4+g)   ^ (r&7)) * 8)]);
      st[t] = mfma16(k0, qf0, z);
      st[t] = mfma16(k1, qf1, st[t]);
    }
    // per-lane max + cross-g sync (2 shuffles)
    float tm = -1e30f;
#pragma unroll
    for (int t = 0; t < 4; t++)
      tm = fmaxf(tm, fmaxf(fmaxf(st[t][0], st[t][1]), fmaxf(st[t][2], st[t][3])));
    tm = fmaxf(tm, __shfl_xor(tm, 16));
    tm = fmaxf(tm, __shfl_xor(tm, 32));
    if (__any(tm - m > 8.f)){              // defer-max (T13)
      float mn = fmaxf(m, tm);
      float al = __expf(m - mn);
      m = mn;
      lsum *= al;
#pragma unroll
      for (int dt = 0; dt < 4; dt++) accO[dt] *= al;
    }
    // exp + pack into 16x16x16 B-frags (k = 4g+j) -- P never leaves registers
    u16x4 p[4];
    float ls = 0.f;
#pragma unroll
    for (int t = 0; t < 4; t++){
#pragma unroll
      for (int j = 0; j < 4; j++){
        float e = __expf(st[t][j] - m);
        ls += e;
        p[t][j] = f2bf(e);
      }
    }
    lsum += ls;
    // PV (swapped): accO[dt] lane holds O[d = dt*16+4g+rr][query r]
#pragma unroll
    for (int s = 0; s < 4; s++)
#pragma unroll
      for (int dt = 0; dt < 4; dt++){
        int row = dt*16 + r;
        u16x4 vf = *reinterpret_cast<const u16x4*>(
            &Vc[row*64 + (((2*s + (g>>1)) ^ (r&7)) * 8) + (g&1)*4]);
        accO[dt] = mfma16k16(vf, p[s], accO[dt]);
      }
  }

  // epilogue: cross-g lsum reduce, normalize, +L, write token-major bf16
  lsum += __shfl_xor(lsum, 16);
  lsum += __shfl_xor(lsum, 32);
  float linv = 1.0f / lsum;
  const int n = q0 + r;
  const u16* lrow = Lb + ((size_t)b * Nn + n) * Cn + h * Dn;
  u16* trow = tok + ((size_t)b * Nn + n) * Cn + h * Dn;
#pragma unroll
  for (int dt = 0; dt < 4; dt++){
    u16x4 lv = *reinterpret_cast<const u16x4*>(lrow + dt*16 + 4*g);
    u16x4 ov;
#pragma unroll
    for (int rr = 0; rr < 4; rr++)
      ov[rr] = f2bf(accO[dt][rr] * linv + bf2f(lv[rr]));
    *reinterpret_cast<u16x4*>(trow + dt*16 + 4*g) = ov;
  }
}

// ---------------- GEMM2: out = Wout @ tok + bout  -> f32 [B][C][N] ----------------
__global__ __launch_bounds__(256) void k_gemm2(const u16* __restrict__ tok, // [B][N][C]
                                               const u16* __restrict__ Wo,  // [C][C]
                                               const float* __restrict__ bout,
                                               float* __restrict__ out){
  __shared__ u16 sA[2*128*32], sB[2*128*32];
  const int ob = blockIdx.x;   // 4 o-blocks of 128
  const int nb = blockIdx.y;   // 8 n-blocks of 128
  const int b  = blockIdx.z;
  const int w = threadIdx.x >> 6, wi = w >> 1, wj = w & 1;
  const int lane = threadIdx.x & 63, r = lane & 15, g = lane >> 4;

  f32x4 acc[4][4];
  const f32x4 z = {0.f, 0.f, 0.f, 0.f};
#pragma unroll
  for (int i = 0; i < 4; i++)
#pragma unroll
    for (int j = 0; j < 4; j++) acc[i][j] = z;

  gemm_nt_128(Wo + (size_t)(ob*128) * Cn, Cn,
              tok + (size_t)b * Nn * Cn + (size_t)(nb*128) * Cn, Cn, sA, sB, acc);

#pragma unroll
  for (int it = 0; it < 4; it++)
#pragma unroll
    for (int jt = 0; jt < 4; jt++)
#pragma unroll
      for (int rr = 0; rr < 4; rr++){
        int o = ob*128 + wi*64 + it*16 + 4*g + rr;
        int n = nb*128 + wj*64 + jt*16 + r;
        out[((size_t)b * Cn + o) * Nn + n] = acc[it][jt][rr] + bout[o];
      }
}

extern "C" void kernel_launch(void* const* d_in, const int* in_sizes, int n_in,
                              void* d_out, int out_size, void* d_ws, size_t ws_size,
                              hipStream_t stream){
  const float* fmap  = (const float*)d_in[0];
  const float* Wqkvl = (const float*)d_in[1];
  const float* Wout  = (const float*)d_in[2];
  const float* bout  = (const float*)d_in[3];
  float* out = (float*)d_out;

  char* ws = (char*)d_ws;
  size_t off = 0;
  auto alloc = [&](size_t bytes) -> void* {
    void* p = ws + off;
    off += (bytes + 255) & ~(size_t)255;
    return p;
  };
  u16* W1bf  = (u16*)alloc((size_t)4*Cn*Cn*2);
  u16* Wobf  = (u16*)alloc((size_t)Cn*Cn*2);
  u16* fmapT = (u16*)alloc((size_t)Bn*Nn*Cn*2);
  u16* Qb    = (u16*)alloc((size_t)Bn*Nn*Cn*2);
  u16* Kb    = (u16*)alloc((size_t)Bn*Nn*Cn*2);
  u16* Lb    = (u16*)alloc((size_t)Bn*Nn*Cn*2);
  u16* Vt    = (u16*)alloc((size_t)Bn*Hn*Dn*Nn*2);
  u16* tok   = fmapT;   // fmapT dead after gemm1; reuse for attention output

  hipLaunchKernelGGL(k_convert, dim3((4*Cn*Cn/4 + 255)/256), dim3(256), 0, stream,
                     Wqkvl, W1bf, 4*Cn*Cn/4);
  hipLaunchKernelGGL(k_convert, dim3((Cn*Cn/4 + 255)/256), dim3(256), 0, stream,
                     Wout, Wobf, Cn*Cn/4);
  hipLaunchKernelGGL(k_transpose, dim3(Nn/32, Cn/32, Bn), dim3(256), 0, stream, fmap, fmapT);
  hipLaunchKernelGGL(k_gemm1, dim3(16, 8, Bn), dim3(256), 0, stream, fmapT, W1bf, Qb, Kb, Vt, Lb);
  hipLaunchKernelGGL(k_attn, dim3(1024), dim3(256), 0, stream, Qb, Kb, Vt, Lb, tok);
  hipLaunchKernelGGL(k_gemm2, dim3(4, 8, Bn), dim3(256), 0, stream, tok, Wobf, bout, out);
}

// Round 6
// 90.285 us; speedup vs baseline: 3.1755x; 1.0680x over previous
//
#include <hip/hip_runtime.h>

#define Bn 8
#define Cn 512
#define Hn 8
#define Dn 64
#define Nn 1024
#define SCALEQ 0.125f

typedef unsigned short u16;
typedef unsigned short u16x8 __attribute__((ext_vector_type(8)));
typedef unsigned short u16x4 __attribute__((ext_vector_type(4)));
typedef short s16x4 __attribute__((ext_vector_type(4)));
typedef float f32x4 __attribute__((ext_vector_type(4)));
typedef __bf16 bf16x8 __attribute__((ext_vector_type(8)));

__device__ __forceinline__ u16 f2bf(float f){
  unsigned u = __float_as_uint(f);
  u += 0x7fffu + ((u >> 16) & 1u);   // RNE
  return (u16)(u >> 16);
}
__device__ __forceinline__ float bf2f(u16 h){
  return __uint_as_float(((unsigned)h) << 16);
}
__device__ __forceinline__ f32x4 mfma16(u16x8 a, u16x8 b, f32x4 c){
  return __builtin_amdgcn_mfma_f32_16x16x32_bf16(
      __builtin_bit_cast(bf16x8, a), __builtin_bit_cast(bf16x8, b), c, 0, 0, 0);
}
// K=16: A/B layout (lane r,g holds k=4g+j) == 16x16 C/D layout -> P stays in registers
__device__ __forceinline__ f32x4 mfma16k16(u16x4 a, u16x4 b, f32x4 c){
  return __builtin_amdgcn_mfma_f32_16x16x16bf16_1k(
      __builtin_bit_cast(s16x4, a), __builtin_bit_cast(s16x4, b), c, 0, 0, 0);
}

// async global->LDS, 16B per lane; dst must be wave-uniform (HW adds lane*16B)
__device__ __forceinline__ void gload16(const u16* src, u16* dst){
  __builtin_amdgcn_global_load_lds(
      (const __attribute__((address_space(1))) unsigned int*)src,
      (__attribute__((address_space(3))) unsigned int*)dst, 16, 0, 0);
}

// ---------------- pre-pass: f32 -> bf16 weight convert (both weights, one launch) ----------
__global__ __launch_bounds__(256) void k_convert2(const float* __restrict__ s1,
                                                  const float* __restrict__ s2,
                                                  u16* __restrict__ d1, u16* __restrict__ d2,
                                                  int n1, int n2){
  int i = blockIdx.x * 256 + threadIdx.x;
  const float* s; u16* d; int j;
  if (i < n1){ s = s1; d = d1; j = i; }
  else { if (i >= n1 + n2) return; s = s2; d = d2; j = i - n1; }
  float4 f = reinterpret_cast<const float4*>(s)[j];
  u16x4 o;
  o[0] = f2bf(f.x); o[1] = f2bf(f.y); o[2] = f2bf(f.z); o[3] = f2bf(f.w);
  reinterpret_cast<u16x4*>(d)[j] = o;
}

// ---------------- pre-pass: fmap [B][C][N] f32 -> fmapT [B][N][C] bf16 ----------------
__global__ __launch_bounds__(256) void k_transpose(const float* __restrict__ fmap,
                                                   u16* __restrict__ fmapT){
  __shared__ float tile[32][33];
  const int n0 = blockIdx.x * 32, c0 = blockIdx.y * 32, b = blockIdx.z;
  const int tx = threadIdx.x & 31, ty = threadIdx.x >> 5;   // 32 x 8
  const float* src = fmap + ((size_t)b * Cn + c0) * Nn + n0;
#pragma unroll
  for (int i = 0; i < 4; i++) tile[ty + 8*i][tx] = src[(size_t)(ty + 8*i) * Nn + tx];
  __syncthreads();
  u16* dst = fmapT + ((size_t)b * Nn + n0) * Cn + c0;
#pragma unroll
  for (int i = 0; i < 4; i++) dst[(size_t)(ty + 8*i) * Cn + tx] = f2bf(tile[tx][ty + 8*i]);
}

// ---- staging: 64 rows x 64 elem (128B rows, 8 chunks of 16B), swizzle chunk^=(row&7) ----
__device__ __forceinline__ void stage64(const u16* g, size_t ldg, u16* lbase, int w, int lane){
#pragma unroll
  for (int s = 0; s < 2; s++){
    int row = s*32 + w*8 + (lane>>3);
    const u16* src = g + (size_t)row*ldg + (((lane&7) ^ (row&7)) * 8);
    u16* dst = lbase + (s*32 + w*8)*64;   // wave-uniform; HW adds lane*16B
    gload16(src, dst);
  }
}
// ---- staging: 128 rows x 32 elem (64B rows, 4 chunks of 16B), swizzle chunk^=(row&3) ----
__device__ __forceinline__ void stage128x32(const u16* g, size_t ldg, u16* lbase, int w, int lane){
#pragma unroll
  for (int s = 0; s < 2; s++){
    int row = s*64 + w*16 + (lane>>2);
    const u16* src = g + (size_t)row*ldg + (((lane&3) ^ (row&3)) * 8);
    u16* dst = lbase + (s*64 + w*16)*32;
    gload16(src, dst);
  }
}

__device__ __forceinline__ void gemm_fma(const u16x8 (&af)[4], const u16x8 (&bf)[4],
                                         f32x4 (&acc)[4][4]){
#pragma unroll
  for (int i = 0; i < 4; i++)
#pragma unroll
    for (int j = 0; j < 4; j++)
      acc[i][j] = mfma16(af[i], bf[j], acc[i][j]);
}

// ---- NT GEMM 128x128 block tile, BK=32, LDS double-buffered, K = Cn ----
__device__ __forceinline__ void gemm_nt_128(const u16* __restrict__ Ap, int lda,
                                            const u16* __restrict__ Bp, int ldb,
                                            u16* sA, u16* sB,  // [2][128*32] each
                                            f32x4 (&acc)[4][4]){
  const int tid = threadIdx.x;
  const int w = tid >> 6, lane = tid & 63, r = lane & 15, g = lane >> 4;
  const int wi = w >> 1, wj = w & 1;
  stage128x32(Ap, lda, sA, w, lane);
  stage128x32(Bp, ldb, sB, w, lane);
  for (int ks = 0; ks < Cn/32; ks++){
    __syncthreads();                       // drains vmcnt -> buf[ks&1] ready; prior reads done
    const int cur = ks & 1;
    if (ks + 1 < Cn/32){
      stage128x32(Ap + (ks+1)*32, lda, sA + (cur^1)*128*32, w, lane);
      stage128x32(Bp + (ks+1)*32, ldb, sB + (cur^1)*128*32, w, lane);
    }
    const u16* Al = sA + cur*128*32;
    const u16* Bl = sB + cur*128*32;
    u16x8 af[4], bf[4];
#pragma unroll
    for (int t = 0; t < 4; t++){
      int ar = wi*64 + t*16 + r;
      af[t] = *reinterpret_cast<const u16x8*>(&Al[ar*32 + ((g ^ (ar&3)) * 8)]);
      int br = wj*64 + t*16 + r;
      bf[t] = *reinterpret_cast<const u16x8*>(&Bl[br*32 + ((g ^ (br&3)) * 8)]);
    }
    gemm_fma(af, bf, acc);
  }
}

// ---------------- GEMM1: qkvL = Wqkvl @ fmap  (per batch) ----------------
__global__ __launch_bounds__(256) void k_gemm1(const u16* __restrict__ fmapT, // [B][N][C]
                                               const u16* __restrict__ W1,    // [2048][C]
                                               u16* __restrict__ Qb, u16* __restrict__ Kb,
                                               u16* __restrict__ Vt, u16* __restrict__ Lb){
  __shared__ u16 sA[2*128*32], sB[2*128*32];
  const int ob = blockIdx.x;           // 16 o-blocks of 128
  const int nb = blockIdx.y;           // 8 n-blocks of 128
  const int b  = blockIdx.z;
  const int w = threadIdx.x >> 6, wi = w >> 1, wj = w & 1;
  const int lane = threadIdx.x & 63, r = lane & 15, g = lane >> 4;
  const int seg = ob >> 2;             // 0=Q 1=K 2=V 3=L

  f32x4 acc[4][4];
  const f32x4 z = {0.f, 0.f, 0.f, 0.f};
#pragma unroll
  for (int i = 0; i < 4; i++)
#pragma unroll
    for (int j = 0; j < 4; j++) acc[i][j] = z;

  const u16* fbase = fmapT + (size_t)b * Nn * Cn;

  if (seg != 2){
    gemm_nt_128(fbase + (size_t)(nb*128) * Cn, Cn, W1 + (size_t)(ob*128) * Cn, Cn, sA, sB, acc);
    u16* dst = (seg == 0) ? Qb : (seg == 1 ? Kb : Lb);
    const float sc = (seg == 0) ? SCALEQ : 1.0f;
#pragma unroll
    for (int it = 0; it < 4; it++)
#pragma unroll
      for (int jt = 0; jt < 4; jt++)
#pragma unroll
        for (int rr = 0; rr < 4; rr++){
          int n = nb*128 + wi*64 + it*16 + 4*g + rr;
          int o = ob*128 + wj*64 + jt*16 + r;
          dst[((size_t)b * Nn + n) * Cn + (o & 511)] = f2bf(acc[it][jt][rr] * sc);
        }
  } else {
    gemm_nt_128(W1 + (size_t)(ob*128) * Cn, Cn, fbase + (size_t)(nb*128) * Cn, Cn, sA, sB, acc);
#pragma unroll
    for (int it = 0; it < 4; it++)
#pragma unroll
      for (int jt = 0; jt < 4; jt++)
#pragma unroll
        for (int rr = 0; rr < 4; rr++){
          int o = ob*128 + wi*64 + it*16 + 4*g + rr;
          int oo = o - 1024;
          int h = oo >> 6, d = oo & 63;
          int n = nb*128 + wj*64 + jt*16 + r;
          Vt[(((size_t)b * Hn + h) * Dn + d) * Nn + n] = f2bf(acc[it][jt][rr]);
        }
  }
}

// ---------------- attention: swapped flash, LDS K/V, reg-P, 2 q-tiles per wave ----------------
__device__ __forceinline__ void attn_tile(const u16* Kc, const u16* Vc,
                                          const u16* kbase, const u16* vbase, int next,
                                          u16* Kn, u16* Vn,
                                          int w, int lane, int r, int g,
                                          u16x8 qA0, u16x8 qA1, u16x8 qB0, u16x8 qB1,
                                          float& mA, float& mB,
                                          f32x4 (&accA)[4], f32x4 (&accB)[4],
                                          f32x4& accSA, f32x4& accSB){
  const f32x4 z = {0.f, 0.f, 0.f, 0.f};
  __syncthreads();                       // current buffers staged; prior reads done
  if (next < 16){
    stage64(kbase + (size_t)next*64*Cn, Cn, Kn, w, lane);
    stage64(vbase + next*64,            Nn, Vn, w, lane);
  }
  // QK^T (swapped): s[t][rr] = S[key = 16t+4g+rr][query r]; K-frags shared by both q-tiles
  f32x4 sA[4], sB[4];
#pragma unroll
  for (int t = 0; t < 4; t++){
    int row = 16*t + r;
    u16x8 k0 = *reinterpret_cast<const u16x8*>(&Kc[row*64 + ((g       ^ (r&7)) * 8)]);
    u16x8 k1 = *reinterpret_cast<const u16x8*>(&Kc[row*64 + (((4+g)   ^ (r&7)) * 8)]);
    sA[t] = mfma16(k0, qA0, z); sA[t] = mfma16(k1, qA1, sA[t]);
    sB[t] = mfma16(k0, qB0, z); sB[t] = mfma16(k1, qB1, sB[t]);
  }
  // per-lane max + cross-g sync (2 shuffles per q-tile)
  float tmA = -1e30f, tmB = -1e30f;
#pragma unroll
  for (int t = 0; t < 4; t++){
    tmA = fmaxf(tmA, fmaxf(fmaxf(sA[t][0], sA[t][1]), fmaxf(sA[t][2], sA[t][3])));
    tmB = fmaxf(tmB, fmaxf(fmaxf(sB[t][0], sB[t][1]), fmaxf(sB[t][2], sB[t][3])));
  }
  tmA = fmaxf(tmA, __shfl_xor(tmA, 16)); tmA = fmaxf(tmA, __shfl_xor(tmA, 32));
  tmB = fmaxf(tmB, __shfl_xor(tmB, 16)); tmB = fmaxf(tmB, __shfl_xor(tmB, 32));
  if (__any(tmA - mA > 8.f)){            // defer-max (T13)
    float mn = fmaxf(mA, tmA), al = __expf(mA - mn);
    mA = mn; accSA *= al;
#pragma unroll
    for (int dt = 0; dt < 4; dt++) accA[dt] *= al;
  }
  if (__any(tmB - mB > 8.f)){
    float mn = fmaxf(mB, tmB), al = __expf(mB - mn);
    mB = mn; accSB *= al;
#pragma unroll
    for (int dt = 0; dt < 4; dt++) accB[dt] *= al;
  }
  // exp + native bf16 pack (compiler pairs into v_cvt_pk_bf16_f32); P stays in registers
  u16x4 pA[4], pB[4];
#pragma unroll
  for (int t = 0; t < 4; t++){
#pragma unroll
    for (int j = 0; j < 4; j++){
      pA[t][j] = __builtin_bit_cast(u16, (__bf16)__expf(sA[t][j] - mA));
      pB[t][j] = __builtin_bit_cast(u16, (__bf16)__expf(sB[t][j] - mB));
    }
  }
  // lsum via ones-MFMA: D[row][col r] = sum_k P[k][r] -- replaces VALU adds + epilogue shuffles
  const u16x4 ones = {0x3F80u, 0x3F80u, 0x3F80u, 0x3F80u};
#pragma unroll
  for (int t = 0; t < 4; t++){
    accSA = mfma16k16(ones, pA[t], accSA);
    accSB = mfma16k16(ones, pB[t], accSB);
  }
  // PV (swapped): V-frags shared by both q-tiles
#pragma unroll
  for (int s = 0; s < 4; s++)
#pragma unroll
    for (int dt = 0; dt < 4; dt++){
      int row = dt*16 + r;
      u16x4 vf = *reinterpret_cast<const u16x4*>(
          &Vc[row*64 + (((2*s + (g>>1)) ^ (r&7)) * 8) + (g&1)*4]);
      accA[dt] = mfma16k16(vf, pA[s], accA[dt]);
      accB[dt] = mfma16k16(vf, pB[s], accB[dt]);
    }
}

__global__ __launch_bounds__(256, 2) void k_attn(const u16* __restrict__ Qb,  // [B][N][C] (pre-scaled)
                                                 const u16* __restrict__ Kb,  // [B][N][C]
                                                 const u16* __restrict__ Vt,  // [B][H][D][N]
                                                 const u16* __restrict__ Lb,  // [B][N][C]
                                                 u16* __restrict__ tok){      // [B][N][C]
  __shared__ u16 Kl[2*64*64], Vl[2*64*64];
  // XCD-bijective swizzle: 512 blocks, the 8 q-blocks of one (b,h) share one XCD's L2
  const int bid = blockIdx.x;
  const int w0 = (bid & 7) * 64 + (bid >> 3);
  const int qblk = w0 & 7, h = (w0 >> 3) & 7, b = w0 >> 6;
  const int w = threadIdx.x >> 6, lane = threadIdx.x & 63;
  const int r = lane & 15, g = lane >> 4;
  const int qA = qblk * 128 + w * 16;          // q-tile A rows qA..qA+15
  const int qB = qA + 64;                      // q-tile B rows qB..qB+15

  const u16* qrowA = Qb + ((size_t)b * Nn + qA + r) * Cn + h * Dn + 8 * g;
  const u16* qrowB = Qb + ((size_t)b * Nn + qB + r) * Cn + h * Dn + 8 * g;
  u16x8 qA0 = *reinterpret_cast<const u16x8*>(qrowA);
  u16x8 qA1 = *reinterpret_cast<const u16x8*>(qrowA + 32);
  u16x8 qB0 = *reinterpret_cast<const u16x8*>(qrowB);
  u16x8 qB1 = *reinterpret_cast<const u16x8*>(qrowB + 32);

  const u16* kbase = Kb + (size_t)b * Nn * Cn + h * Dn;
  const u16* vbase = Vt + ((size_t)b * Hn + h) * Dn * Nn;

  f32x4 accA[4], accB[4];
  const f32x4 z = {0.f, 0.f, 0.f, 0.f};
#pragma unroll
  for (int dt = 0; dt < 4; dt++){ accA[dt] = z; accB[dt] = z; }
  f32x4 accSA = z, accSB = z;
  float mA = -1e30f, mB = -1e30f;

  u16* Kl0 = Kl, *Kl1 = Kl + 64*64;
  u16* Vl0 = Vl, *Vl1 = Vl + 64*64;
  stage64(kbase, Cn, Kl0, w, lane);
  stage64(vbase, Nn, Vl0, w, lane);

  for (int tile = 0; tile < 16; tile += 2){   // manual 2x unroll: compile-time buffer ptrs
    attn_tile(Kl0, Vl0, kbase, vbase, tile + 1, Kl1, Vl1, w, lane, r, g,
              qA0, qA1, qB0, qB1, mA, mB, accA, accB, accSA, accSB);
    attn_tile(Kl1, Vl1, kbase, vbase, tile + 2, Kl0, Vl0, w, lane, r, g,
              qA0, qA1, qB0, qB1, mA, mB, accA, accB, accSA, accSB);
  }

  // epilogue: lsum already reduced by ones-MFMA (all components equal); +L, write bf16
  float linvA = 1.0f / accSA[0];
  float linvB = 1.0f / accSB[0];
#pragma unroll
  for (int half = 0; half < 2; half++){
    const int n = (half ? qB : qA) + r;
    const float linv = half ? linvB : linvA;
    const f32x4* acc = half ? accB : accA;
    const u16* lrow = Lb + ((size_t)b * Nn + n) * Cn + h * Dn;
    u16* trow = tok + ((size_t)b * Nn + n) * Cn + h * Dn;
#pragma unroll
    for (int dt = 0; dt < 4; dt++){
      u16x4 lv = *reinterpret_cast<const u16x4*>(lrow + dt*16 + 4*g);
      u16x4 ov;
#pragma unroll
      for (int rr = 0; rr < 4; rr++)
        ov[rr] = f2bf(acc[dt][rr] * linv + bf2f(lv[rr]));
      *reinterpret_cast<u16x4*>(trow + dt*16 + 4*g) = ov;
    }
  }
}

// ---------------- GEMM2: out = Wout @ tok + bout  -> f32 [B][C][N] ----------------
__global__ __launch_bounds__(256) void k_gemm2(const u16* __restrict__ tok, // [B][N][C]
                                               const u16* __restrict__ Wo,  // [C][C]
                                               const float* __restrict__ bout,
                                               float* __restrict__ out){
  __shared__ u16 sA[2*128*32], sB[2*128*32];
  const int ob = blockIdx.x;   // 4 o-blocks of 128
  const int nb = blockIdx.y;   // 8 n-blocks of 128
  const int b  = blockIdx.z;
  const int w = threadIdx.x >> 6, wi = w >> 1, wj = w & 1;
  const int lane = threadIdx.x & 63, r = lane & 15, g = lane >> 4;

  f32x4 acc[4][4];
  const f32x4 z = {0.f, 0.f, 0.f, 0.f};
#pragma unroll
  for (int i = 0; i < 4; i++)
#pragma unroll
    for (int j = 0; j < 4; j++) acc[i][j] = z;

  gemm_nt_128(Wo + (size_t)(ob*128) * Cn, Cn,
              tok + (size_t)b * Nn * Cn + (size_t)(nb*128) * Cn, Cn, sA, sB, acc);

#pragma unroll
  for (int it = 0; it < 4; it++)
#pragma unroll
    for (int jt = 0; jt < 4; jt++)
#pragma unroll
      for (int rr = 0; rr < 4; rr++){
        int o = ob*128 + wi*64 + it*16 + 4*g + rr;
        int n = nb*128 + wj*64 + jt*16 + r;
        out[((size_t)b * Cn + o) * Nn + n] = acc[it][jt][rr] + bout[o];
      }
}

extern "C" void kernel_launch(void* const* d_in, const int* in_sizes, int n_in,
                              void* d_out, int out_size, void* d_ws, size_t ws_size,
                              hipStream_t stream){
  const float* fmap  = (const float*)d_in[0];
  const float* Wqkvl = (const float*)d_in[1];
  const float* Wout  = (const float*)d_in[2];
  const float* bout  = (const float*)d_in[3];
  float* out = (float*)d_out;

  char* ws = (char*)d_ws;
  size_t off = 0;
  auto alloc = [&](size_t bytes) -> void* {
    void* p = ws + off;
    off += (bytes + 255) & ~(size_t)255;
    return p;
  };
  u16* W1bf  = (u16*)alloc((size_t)4*Cn*Cn*2);
  u16* Wobf  = (u16*)alloc((size_t)Cn*Cn*2);
  u16* fmapT = (u16*)alloc((size_t)Bn*Nn*Cn*2);
  u16* Qb    = (u16*)alloc((size_t)Bn*Nn*Cn*2);
  u16* Kb    = (u16*)alloc((size_t)Bn*Nn*Cn*2);
  u16* Lb    = (u16*)alloc((size_t)Bn*Nn*Cn*2);
  u16* Vt    = (u16*)alloc((size_t)Bn*Hn*Dn*Nn*2);
  u16* tok   = fmapT;   // fmapT dead after gemm1; reuse for attention output

  const int n1 = 4*Cn*Cn/4, n2 = Cn*Cn/4;
  hipLaunchKernelGGL(k_convert2, dim3((n1 + n2 + 255)/256), dim3(256), 0, stream,
                     Wqkvl, Wout, W1bf, Wobf, n1, n2);
  hipLaunchKernelGGL(k_transpose, dim3(Nn/32, Cn/32, Bn), dim3(256), 0, stream, fmap, fmapT);
  hipLaunchKernelGGL(k_gemm1, dim3(16, 8, Bn), dim3(256), 0, stream, fmapT, W1bf, Qb, Kb, Vt, Lb);
  hipLaunchKernelGGL(k_attn, dim3(512), dim3(256), 0, stream, Qb, Kb, Vt, Lb, tok);
  hipLaunchKernelGGL(k_gemm2, dim3(4, 8, Bn), dim3(256), 0, stream, tok, Wobf, bout, out);
}

// Round 7
// 90.105 us; speedup vs baseline: 3.1818x; 1.0020x over previous
//
#include <hip/hip_runtime.h>

#define Bn 8
#define Cn 512
#define Hn 8
#define Dn 64
#define Nn 1024
#define SCALEQ 0.125f

typedef unsigned short u16;
typedef unsigned short u16x8 __attribute__((ext_vector_type(8)));
typedef unsigned short u16x4 __attribute__((ext_vector_type(4)));
typedef short s16x4 __attribute__((ext_vector_type(4)));
typedef float f32x4 __attribute__((ext_vector_type(4)));
typedef __bf16 bf16x8 __attribute__((ext_vector_type(8)));

__device__ __forceinline__ u16 f2bf(float f){
  unsigned u = __float_as_uint(f);
  u += 0x7fffu + ((u >> 16) & 1u);   // RNE
  return (u16)(u >> 16);
}
__device__ __forceinline__ float bf2f(u16 h){
  return __uint_as_float(((unsigned)h) << 16);
}
__device__ __forceinline__ f32x4 mfma16(u16x8 a, u16x8 b, f32x4 c){
  return __builtin_amdgcn_mfma_f32_16x16x32_bf16(
      __builtin_bit_cast(bf16x8, a), __builtin_bit_cast(bf16x8, b), c, 0, 0, 0);
}
// K=16: A/B layout (lane r,g holds k=4g+j) == 16x16 C/D layout -> P stays in registers
__device__ __forceinline__ f32x4 mfma16k16(u16x4 a, u16x4 b, f32x4 c){
  return __builtin_amdgcn_mfma_f32_16x16x16bf16_1k(
      __builtin_bit_cast(s16x4, a), __builtin_bit_cast(s16x4, b), c, 0, 0, 0);
}

// async global->LDS, 16B per lane; dst must be wave-uniform (HW adds lane*16B)
__device__ __forceinline__ void gload16(const u16* src, u16* dst){
  __builtin_amdgcn_global_load_lds(
      (const __attribute__((address_space(1))) unsigned int*)src,
      (__attribute__((address_space(3))) unsigned int*)dst, 16, 0, 0);
}

// ---------------- pre-pass: f32 -> bf16 weight convert (both weights, one launch) ----------
__global__ __launch_bounds__(256) void k_convert2(const float* __restrict__ s1,
                                                  const float* __restrict__ s2,
                                                  u16* __restrict__ d1, u16* __restrict__ d2,
                                                  int n1, int n2){
  int i = blockIdx.x * 256 + threadIdx.x;
  const float* s; u16* d; int j;
  if (i < n1){ s = s1; d = d1; j = i; }
  else { if (i >= n1 + n2) return; s = s2; d = d2; j = i - n1; }
  float4 f = reinterpret_cast<const float4*>(s)[j];
  u16x4 o;
  o[0] = f2bf(f.x); o[1] = f2bf(f.y); o[2] = f2bf(f.z); o[3] = f2bf(f.w);
  reinterpret_cast<u16x4*>(d)[j] = o;
}

// ---------------- pre-pass: fmap [B][C][N] f32 -> fmapT [B][N][C] bf16 ----------------
// 32n x 64c tiles; u16x8 (16B) stores
__global__ __launch_bounds__(256) void k_transpose(const float* __restrict__ fmap,
                                                   u16* __restrict__ fmapT){
  __shared__ float tile[64][33];
  const int n0 = blockIdx.x * 32, c0 = blockIdx.y * 64, b = blockIdx.z;
  const int tx = threadIdx.x & 31, ty = threadIdx.x >> 5;   // 32 x 8
  const float* src = fmap + ((size_t)b * Cn + c0) * Nn + n0;
#pragma unroll
  for (int i = 0; i < 8; i++) tile[ty + 8*i][tx] = src[(size_t)(ty + 8*i) * Nn + tx];
  __syncthreads();
  const int nr = threadIdx.x >> 3;          // 0..31 (n within tile)
  const int cj = (threadIdx.x & 7) * 8;     // 0..56 (c within tile)
  u16x8 o;
#pragma unroll
  for (int k = 0; k < 8; k++) o[k] = f2bf(tile[cj + k][nr]);
  *reinterpret_cast<u16x8*>(fmapT + ((size_t)b * Nn + n0 + nr) * Cn + c0 + cj) = o;
}

// ---- staging: K-tile 128 rows x 64 elem (128B rows), swizzle chunk^=(row&7) ----
__device__ __forceinline__ void stageK(const u16* g, u16* lbase, int w, int lane){
#pragma unroll
  for (int s = 0; s < 4; s++){
    int row = s*32 + w*8 + (lane>>3);
    gload16(g + (size_t)row*Cn + (((lane&7) ^ (row&7)) * 8), lbase + (s*32 + w*8)*64);
  }
}
// ---- staging: V-tile 64 rows x 128 elem (256B rows), swizzle chunk^=(row&7) ----
__device__ __forceinline__ void stageV(const u16* g, u16* lbase, int w, int lane){
#pragma unroll
  for (int s = 0; s < 4; s++){
    int row = s*16 + w*4 + (lane>>4);
    gload16(g + (size_t)row*Nn + (((lane&15) ^ (row&7)) * 8), lbase + (s*16 + w*4)*128);
  }
}
// ---- staging: 128 rows x 32 elem (64B rows), swizzle chunk^=(row&3) ----
__device__ __forceinline__ void stage128x32(const u16* g, size_t ldg, u16* lbase, int w, int lane){
#pragma unroll
  for (int s = 0; s < 2; s++){
    int row = s*64 + w*16 + (lane>>2);
    gload16(g + (size_t)row*ldg + (((lane&3) ^ (row&3)) * 8), lbase + (s*64 + w*16)*32);
  }
}

__device__ __forceinline__ void gemm_fma(const u16x8 (&af)[4], const u16x8 (&bf)[4],
                                         f32x4 (&acc)[4][4]){
#pragma unroll
  for (int i = 0; i < 4; i++)
#pragma unroll
    for (int j = 0; j < 4; j++)
      acc[i][j] = mfma16(af[i], bf[j], acc[i][j]);
}

// ---- NT GEMM 128x128 block tile, BK=32, LDS double-buffered, K = Cn ----
__device__ __forceinline__ void gemm_nt_128(const u16* __restrict__ Ap, int lda,
                                            const u16* __restrict__ Bp, int ldb,
                                            u16* sA, u16* sB,  // [2][128*32] each
                                            f32x4 (&acc)[4][4]){
  const int tid = threadIdx.x;
  const int w = tid >> 6, lane = tid & 63, r = lane & 15, g = lane >> 4;
  const int wi = w >> 1, wj = w & 1;
  stage128x32(Ap, lda, sA, w, lane);
  stage128x32(Bp, ldb, sB, w, lane);
  for (int ks = 0; ks < Cn/32; ks++){
    __syncthreads();                       // drains vmcnt -> buf[ks&1] ready; prior reads done
    const int cur = ks & 1;
    if (ks + 1 < Cn/32){
      stage128x32(Ap + (ks+1)*32, lda, sA + (cur^1)*128*32, w, lane);
      stage128x32(Bp + (ks+1)*32, ldb, sB + (cur^1)*128*32, w, lane);
    }
    const u16* Al = sA + cur*128*32;
    const u16* Bl = sB + cur*128*32;
    u16x8 af[4], bf[4];
#pragma unroll
    for (int t = 0; t < 4; t++){
      int ar = wi*64 + t*16 + r;
      af[t] = *reinterpret_cast<const u16x8*>(&Al[ar*32 + ((g ^ (ar&3)) * 8)]);
      int br = wj*64 + t*16 + r;
      bf[t] = *reinterpret_cast<const u16x8*>(&Bl[br*32 + ((g ^ (br&3)) * 8)]);
    }
    gemm_fma(af, bf, acc);
  }
}

// ---------------- GEMM1: qkvL = Wqkvl @ fmap  (per batch) ----------------
// 1-D grid 1024, chunked XCD swizzle: each XCD owns one batch (A-panel + W L2-local)
__global__ __launch_bounds__(256) void k_gemm1(const u16* __restrict__ fmapT, // [B][N][C]
                                               const u16* __restrict__ W1,    // [2048][C]
                                               u16* __restrict__ Qb, u16* __restrict__ Kb,
                                               u16* __restrict__ Vt, u16* __restrict__ Lb){
  __shared__ u16 sA[2*128*32], sB[2*128*32];
  const int lin = blockIdx.x;
  const int wid = (lin & 7) * 128 + (lin >> 3);
  const int ob = wid & 15, nb = (wid >> 4) & 7, b = wid >> 7;
  const int w = threadIdx.x >> 6, wi = w >> 1, wj = w & 1;
  const int lane = threadIdx.x & 63, r = lane & 15, g = lane >> 4;
  const int seg = ob >> 2;             // 0=Q 1=K 2=V 3=L

  f32x4 acc[4][4];
  const f32x4 z = {0.f, 0.f, 0.f, 0.f};
#pragma unroll
  for (int i = 0; i < 4; i++)
#pragma unroll
    for (int j = 0; j < 4; j++) acc[i][j] = z;

  const u16* fbase = fmapT + (size_t)b * Nn * Cn;

  if (seg != 2){
    gemm_nt_128(fbase + (size_t)(nb*128) * Cn, Cn, W1 + (size_t)(ob*128) * Cn, Cn, sA, sB, acc);
    u16* dst = (seg == 0) ? Qb : (seg == 1 ? Kb : Lb);
    const float sc = (seg == 0) ? SCALEQ : 1.0f;
#pragma unroll
    for (int it = 0; it < 4; it++)
#pragma unroll
      for (int jt = 0; jt < 4; jt++)
#pragma unroll
        for (int rr = 0; rr < 4; rr++){
          int n = nb*128 + wi*64 + it*16 + 4*g + rr;
          int o = ob*128 + wj*64 + jt*16 + r;
          dst[((size_t)b * Nn + n) * Cn + (o & 511)] = f2bf(acc[it][jt][rr] * sc);
        }
  } else {
    gemm_nt_128(W1 + (size_t)(ob*128) * Cn, Cn, fbase + (size_t)(nb*128) * Cn, Cn, sA, sB, acc);
#pragma unroll
    for (int it = 0; it < 4; it++)
#pragma unroll
      for (int jt = 0; jt < 4; jt++)
#pragma unroll
        for (int rr = 0; rr < 4; rr++){
          int o = ob*128 + wi*64 + it*16 + 4*g + rr;
          int oo = o - 1024;
          int h = oo >> 6, d = oo & 63;
          int n = nb*128 + wj*64 + jt*16 + r;
          Vt[(((size_t)b * Hn + h) * Dn + d) * Nn + n] = f2bf(acc[it][jt][rr]);
        }
  }
}

// ---------------- attention: swapped flash, LDS K/V (KVBLK=128), reg-P, 2 q-tiles/wave -------
__device__ __forceinline__ void attn_tile(const u16* Kc, const u16* Vc,
                                          const u16* kbase, const u16* vbase, int next,
                                          u16* Kn, u16* Vn,
                                          int w, int lane, int r, int g,
                                          u16x8 qA0, u16x8 qA1, u16x8 qB0, u16x8 qB1,
                                          float& mA, float& mB,
                                          f32x4 (&accA)[4], f32x4 (&accB)[4],
                                          f32x4& accSA, f32x4& accSB){
  const f32x4 z = {0.f, 0.f, 0.f, 0.f};
  __syncthreads();                       // current buffers staged; prior reads done
  if (next < 8){
    stageK(kbase + (size_t)next*128*Cn, Kn, w, lane);
    stageV(vbase + next*128,            Vn, w, lane);
  }
  // QK^T (swapped): s[t][rr] = S[key = 16t+4g+rr][query r]; K-frags shared by both q-tiles
  f32x4 sA[8], sB[8];
#pragma unroll
  for (int t = 0; t < 8; t++){
    int row = 16*t + r;
    u16x8 k0 = *reinterpret_cast<const u16x8*>(&Kc[row*64 + ((g     ^ (r&7)) * 8)]);
    u16x8 k1 = *reinterpret_cast<const u16x8*>(&Kc[row*64 + (((4+g) ^ (r&7)) * 8)]);
    sA[t] = mfma16(k0, qA0, z); sA[t] = mfma16(k1, qA1, sA[t]);
    sB[t] = mfma16(k0, qB0, z); sB[t] = mfma16(k1, qB1, sB[t]);
  }
  // per-lane max + cross-g sync (2 shuffles per q-tile)
  float tmA = -1e30f, tmB = -1e30f;
#pragma unroll
  for (int t = 0; t < 8; t++){
    tmA = fmaxf(tmA, fmaxf(fmaxf(sA[t][0], sA[t][1]), fmaxf(sA[t][2], sA[t][3])));
    tmB = fmaxf(tmB, fmaxf(fmaxf(sB[t][0], sB[t][1]), fmaxf(sB[t][2], sB[t][3])));
  }
  tmA = fmaxf(tmA, __shfl_xor(tmA, 16)); tmA = fmaxf(tmA, __shfl_xor(tmA, 32));
  tmB = fmaxf(tmB, __shfl_xor(tmB, 16)); tmB = fmaxf(tmB, __shfl_xor(tmB, 32));
  if (__any(tmA - mA > 8.f)){            // defer-max (T13)
    float mn = fmaxf(mA, tmA), al = __expf(mA - mn);
    mA = mn; accSA *= al;
#pragma unroll
    for (int dt = 0; dt < 4; dt++) accA[dt] *= al;
  }
  if (__any(tmB - mB > 8.f)){
    float mn = fmaxf(mB, tmB), al = __expf(mB - mn);
    mB = mn; accSB *= al;
#pragma unroll
    for (int dt = 0; dt < 4; dt++) accB[dt] *= al;
  }
  // exp + native bf16 pack; P stays in registers
  u16x4 pA[8], pB[8];
#pragma unroll
  for (int t = 0; t < 8; t++){
#pragma unroll
    for (int j = 0; j < 4; j++){
      pA[t][j] = __builtin_bit_cast(u16, (__bf16)__expf(sA[t][j] - mA));
      pB[t][j] = __builtin_bit_cast(u16, (__bf16)__expf(sB[t][j] - mB));
    }
  }
  // lsum via ones-MFMA
  const u16x4 ones = {0x3F80u, 0x3F80u, 0x3F80u, 0x3F80u};
#pragma unroll
  for (int t = 0; t < 8; t++){
    accSA = mfma16k16(ones, pA[t], accSA);
    accSB = mfma16k16(ones, pB[t], accSB);
  }
  // PV (swapped): V-frags shared by both q-tiles
#pragma unroll
  for (int s = 0; s < 8; s++)
#pragma unroll
    for (int dt = 0; dt < 4; dt++){
      int row = dt*16 + r;
      u16x4 vf = *reinterpret_cast<const u16x4*>(
          &Vc[row*128 + (((2*s + (g>>1)) ^ (r&7)) * 8) + (g&1)*4]);
      accA[dt] = mfma16k16(vf, pA[s], accA[dt]);
      accB[dt] = mfma16k16(vf, pB[s], accB[dt]);
    }
}

__global__ __launch_bounds__(256, 2) void k_attn(const u16* __restrict__ Qb,  // [B][N][C] (pre-scaled)
                                                 const u16* __restrict__ Kb,  // [B][N][C]
                                                 const u16* __restrict__ Vt,  // [B][H][D][N]
                                                 const u16* __restrict__ Lb,  // [B][N][C]
                                                 u16* __restrict__ tok){      // [B][N][C]
  __shared__ u16 Kl[2*128*64], Vl[2*64*128];   // 64 KB total
  // XCD-bijective swizzle: 512 blocks, the 8 q-blocks of one (b,h) share one XCD's L2
  const int bid = blockIdx.x;
  const int w0 = (bid & 7) * 64 + (bid >> 3);
  const int qblk = w0 & 7, h = (w0 >> 3) & 7, b = w0 >> 6;
  const int w = threadIdx.x >> 6, lane = threadIdx.x & 63;
  const int r = lane & 15, g = lane >> 4;
  const int qA = qblk * 128 + w * 16;
  const int qB = qA + 64;

  const u16* qrowA = Qb + ((size_t)b * Nn + qA + r) * Cn + h * Dn + 8 * g;
  const u16* qrowB = Qb + ((size_t)b * Nn + qB + r) * Cn + h * Dn + 8 * g;
  u16x8 qA0 = *reinterpret_cast<const u16x8*>(qrowA);
  u16x8 qA1 = *reinterpret_cast<const u16x8*>(qrowA + 32);
  u16x8 qB0 = *reinterpret_cast<const u16x8*>(qrowB);
  u16x8 qB1 = *reinterpret_cast<const u16x8*>(qrowB + 32);

  const u16* kbase = Kb + (size_t)b * Nn * Cn + h * Dn;
  const u16* vbase = Vt + ((size_t)b * Hn + h) * Dn * Nn;

  f32x4 accA[4], accB[4];
  const f32x4 z = {0.f, 0.f, 0.f, 0.f};
#pragma unroll
  for (int dt = 0; dt < 4; dt++){ accA[dt] = z; accB[dt] = z; }
  f32x4 accSA = z, accSB = z;
  float mA = -1e30f, mB = -1e30f;

  u16* Kl0 = Kl, *Kl1 = Kl + 128*64;
  u16* Vl0 = Vl, *Vl1 = Vl + 64*128;
  stageK(kbase, Kl0, w, lane);
  stageV(vbase, Vl0, w, lane);

  for (int tile = 0; tile < 8; tile += 2){   // manual 2x unroll: compile-time buffer ptrs
    attn_tile(Kl0, Vl0, kbase, vbase, tile + 1, Kl1, Vl1, w, lane, r, g,
              qA0, qA1, qB0, qB1, mA, mB, accA, accB, accSA, accSB);
    attn_tile(Kl1, Vl1, kbase, vbase, tile + 2, Kl0, Vl0, w, lane, r, g,
              qA0, qA1, qB0, qB1, mA, mB, accA, accB, accSA, accSB);
  }

  // epilogue: lsum already reduced by ones-MFMA; +L, write token-major bf16
  float linvA = 1.0f / accSA[0];
  float linvB = 1.0f / accSB[0];
#pragma unroll
  for (int half = 0; half < 2; half++){
    const int n = (half ? qB : qA) + r;
    const float linv = half ? linvB : linvA;
    const f32x4* acc = half ? accB : accA;
    const u16* lrow = Lb + ((size_t)b * Nn + n) * Cn + h * Dn;
    u16* trow = tok + ((size_t)b * Nn + n) * Cn + h * Dn;
#pragma unroll
    for (int dt = 0; dt < 4; dt++){
      u16x4 lv = *reinterpret_cast<const u16x4*>(lrow + dt*16 + 4*g);
      u16x4 ov;
#pragma unroll
      for (int rr = 0; rr < 4; rr++)
        ov[rr] = f2bf(acc[dt][rr] * linv + bf2f(lv[rr]));
      *reinterpret_cast<u16x4*>(trow + dt*16 + 4*g) = ov;
    }
  }
}

// ---------------- GEMM2: out = Wout @ tok + bout  -> f32 [B][C][N] ----------------
// 1-D grid 256, chunked XCD swizzle: each XCD owns one batch
__global__ __launch_bounds__(256) void k_gemm2(const u16* __restrict__ tok, // [B][N][C]
                                               const u16* __restrict__ Wo,  // [C][C]
                                               const float* __restrict__ bout,
                                               float* __restrict__ out){
  __shared__ u16 sA[2*128*32], sB[2*128*32];
  const int lin = blockIdx.x;
  const int wid = (lin & 7) * 32 + (lin >> 3);
  const int ob = wid & 3, nb = (wid >> 2) & 7, b = wid >> 5;
  const int w = threadIdx.x >> 6, wi = w >> 1, wj = w & 1;
  const int lane = threadIdx.x & 63, r = lane & 15, g = lane >> 4;

  f32x4 acc[4][4];
  const f32x4 z = {0.f, 0.f, 0.f, 0.f};
#pragma unroll
  for (int i = 0; i < 4; i++)
#pragma unroll
    for (int j = 0; j < 4; j++) acc[i][j] = z;

  gemm_nt_128(Wo + (size_t)(ob*128) * Cn, Cn,
              tok + (size_t)b * Nn * Cn + (size_t)(nb*128) * Cn, Cn, sA, sB, acc);

#pragma unroll
  for (int it = 0; it < 4; it++)
#pragma unroll
    for (int jt = 0; jt < 4; jt++)
#pragma unroll
      for (int rr = 0; rr < 4; rr++){
        int o = ob*128 + wi*64 + it*16 + 4*g + rr;
        int n = nb*128 + wj*64 + jt*16 + r;
        out[((size_t)b * Cn + o) * Nn + n] = acc[it][jt][rr] + bout[o];
      }
}

extern "C" void kernel_launch(void* const* d_in, const int* in_sizes, int n_in,
                              void* d_out, int out_size, void* d_ws, size_t ws_size,
                              hipStream_t stream){
  const float* fmap  = (const float*)d_in[0];
  const float* Wqkvl = (const float*)d_in[1];
  const float* Wout  = (const float*)d_in[2];
  const float* bout  = (const float*)d_in[3];
  float* out = (float*)d_out;

  char* ws = (char*)d_ws;
  size_t off = 0;
  auto alloc = [&](size_t bytes) -> void* {
    void* p = ws + off;
    off += (bytes + 255) & ~(size_t)255;
    return p;
  };
  u16* W1bf  = (u16*)alloc((size_t)4*Cn*Cn*2);
  u16* Wobf  = (u16*)alloc((size_t)Cn*Cn*2);
  u16* fmapT = (u16*)alloc((size_t)Bn*Nn*Cn*2);
  u16* Qb    = (u16*)alloc((size_t)Bn*Nn*Cn*2);
  u16* Kb    = (u16*)alloc((size_t)Bn*Nn*Cn*2);
  u16* Lb    = (u16*)alloc((size_t)Bn*Nn*Cn*2);
  u16* Vt    = (u16*)alloc((size_t)Bn*Hn*Dn*Nn*2);
  u16* tok   = fmapT;   // fmapT dead after gemm1; reuse for attention output

  const int n1 = 4*Cn*Cn/4, n2 = Cn*Cn/4;
  hipLaunchKernelGGL(k_convert2, dim3((n1 + n2 + 255)/256), dim3(256), 0, stream,
                     Wqkvl, Wout, W1bf, Wobf, n1, n2);
  hipLaunchKernelGGL(k_transpose, dim3(Nn/32, Cn/64, Bn), dim3(256), 0, stream, fmap, fmapT);
  hipLaunchKernelGGL(k_gemm1, dim3(1024), dim3(256), 0, stream, fmapT, W1bf, Qb, Kb, Vt, Lb);
  hipLaunchKernelGGL(k_attn, dim3(512), dim3(256), 0, stream, Qb, Kb, Vt, Lb, tok);
  hipLaunchKernelGGL(k_gemm2, dim3(256), dim3(256), 0, stream, tok, Wobf, bout, out);
}